// Round 3
// baseline (680.413 us; speedup 1.0000x reference)
//
#include <hip/hip_runtime.h>
#include <math.h>

// Problem constants (fixed by setup_inputs)
#define BB 2
#define CC 64
#define DD 64
#define HH 128
#define WW 128
#define HW (HH * WW)

#define ROWS_PER_BLOCK 16          // 8 hr-groups x RPT=2 rows
#define NHT (HH / ROWS_PER_BLOCK)  // 8
#define NPART NHT                  // 8 partials per (b,c)

// ---------------------------------------------------------------------------
// Kernel 1: streaming 19-tap Laplacian, per-block partial |lap| sum.
//   S5(d) = -6*c + (N+S+E+W)                  (outer slices)
//   S9(d) = 24*c - 6*(N+S+E+W) + diagonals    (mid slice)
//   lap(d) = S9(d) + S5(d-1) + S5(d+1)        (zero pad outside volume)
// Thread owns (h0..h0+1, w0..w0+3). Whole d-range (64 slices) per block.
// 1-deep software pipeline: slice d+2 loads issued while computing output d.
// W-halo comes from lane shuffles, not extra loads.
// ---------------------------------------------------------------------------
__global__ __launch_bounds__(256, 4) void lap_score_partial(
    const float* __restrict__ x, float* __restrict__ partials) {
  const int ht  = blockIdx.x;
  const int bc  = blockIdx.y;
  const int tid = threadIdx.x;
  const int hr  = tid >> 5;  // 0..7
  const int wg  = tid & 31;  // 0..31
  const int h0  = ht * ROWS_PER_BLOCK + hr * 2;
  const int w0  = wg * 4;

  const float* chan = x + (size_t)bc * ((size_t)DD * HW);

  // rows hh = h0-1 .. h0+2: clamped offsets + zero masks (uniform over d)
  int rowoff[4];
  float maskf[4];
#pragma unroll
  for (int rr = 0; rr < 4; ++rr) {
    int hh = h0 - 1 + rr;
    bool valid = (hh >= 0) && (hh < HH);
    int hc = valid ? hh : (hh < 0 ? 0 : HH - 1);
    rowoff[rr] = hc * WW + w0;
    maskf[rr] = valid ? 1.f : 0.f;
  }

  // issue 4 row loads of slice d (no waits here)
  auto issue = [&](int d, float4 r[4]) {
    const float* sp = chan + (size_t)d * HW;
#pragma unroll
    for (int rr = 0; rr < 4; ++rr)
      r[rr] = *reinterpret_cast<const float4*>(sp + rowoff[rr]);
  };

  // compute S5,S9 (2 rows x 4 cols) of a previously-loaded slice
  auto consume = [&](const float4 r[4], float s5[2][4], float s9[2][4]) {
    float cen[4][4], hp[4][4];
#pragma unroll
    for (int rr = 0; rr < 4; ++rr) {
      float m = maskf[rr];
      float a1 = r[rr].x * m, a2 = r[rr].y * m, a3 = r[rr].z * m,
            a4 = r[rr].w * m;
      float a0 = __shfl_up(a4, 1);
      a0 = (wg == 0) ? 0.f : a0;
      float a5 = __shfl_down(a1, 1);
      a5 = (wg == 31) ? 0.f : a5;
      cen[rr][0] = a1; cen[rr][1] = a2; cen[rr][2] = a3; cen[rr][3] = a4;
      hp[rr][0] = a0 + a2; hp[rr][1] = a1 + a3;
      hp[rr][2] = a2 + a4; hp[rr][3] = a3 + a5;
    }
#pragma unroll
    for (int i = 0; i < 2; ++i)
#pragma unroll
      for (int j = 0; j < 4; ++j) {
        float c = cen[i + 1][j];
        float t = hp[i + 1][j] + cen[i][j] + cen[i + 2][j];  // N+S+E+W
        s5[i][j] = fmaf(-6.f, c, t);
        s9[i][j] = fmaf(24.f, c, fmaf(-6.f, t, hp[i][j] + hp[i + 2][j]));
      }
  };

  float4 rawA[4], rawB[4];
  float s5p[2][4], s5c[2][4], s9c[2][4], s5n[2][4], s9n[2][4];
  float acc = 0.f;

  issue(0, rawA);
  issue(1, rawB);
  consume(rawA, s5c, s9c);  // slice 0
#pragma unroll
  for (int i = 0; i < 2; ++i)
#pragma unroll
    for (int j = 0; j < 4; ++j) s5p[i][j] = 0.f;  // S5(-1) = 0

  // body for output slice d: cur holds slice d+1; issue slice d+2 into nxt
  auto body = [&](int d, float4 cur[4], float4 nxt[4]) {
    if (d + 2 < DD) issue(d + 2, nxt);
    if (d + 1 < DD) {
      consume(cur, s5n, s9n);
    } else {
#pragma unroll
      for (int i = 0; i < 2; ++i)
#pragma unroll
        for (int j = 0; j < 4; ++j) { s5n[i][j] = 0.f; s9n[i][j] = 0.f; }
    }
#pragma unroll
    for (int i = 0; i < 2; ++i)
#pragma unroll
      for (int j = 0; j < 4; ++j) {
        acc += fabsf(s9c[i][j] + s5p[i][j] + s5n[i][j]);
        s5p[i][j] = s5c[i][j];
        s5c[i][j] = s5n[i][j];
        s9c[i][j] = s9n[i][j];
      }
  };

  for (int d = 0; d < DD; d += 2) {  // static double-buffer indices
    body(d, rawB, rawA);
    body(d + 1, rawA, rawB);
  }

  // deterministic block tree reduction
  __shared__ float red[256];
  red[tid] = acc;
  __syncthreads();
  for (int s = 128; s > 0; s >>= 1) {
    if (tid < s) red[tid] += red[tid + s];
    __syncthreads();
  }
  if (tid == 0) partials[(size_t)bc * NPART + ht] = red[0];
}

// ---------------------------------------------------------------------------
// Kernel 2: fused score-reduce + top-k rank selection.
// Matches jax.lax.top_k: descending, ties -> lower index first.
// ---------------------------------------------------------------------------
__global__ void score_topk(const float* __restrict__ partials,
                           int* __restrict__ idx, int k) {
  const int b = blockIdx.x;
  const int c = threadIdx.x;  // 0..C-1
  const float* pp = partials + (size_t)(b * CC + c) * NPART;
  float s = 0.f;
#pragma unroll
  for (int i = 0; i < NPART; ++i) s += pp[i];  // fixed serial order
  __shared__ float sm[CC];
  sm[c] = s;
  __syncthreads();
  int rank = 0;
  for (int j = 0; j < CC; ++j) {
    float u = sm[j];
    rank += (u > s) || (u == s && j < c);
  }
  if (rank < k) idx[b * k + rank] = c;
}

// ---------------------------------------------------------------------------
// Kernel 3: gather selected channels (pure float4 copy).
// ---------------------------------------------------------------------------
__global__ __launch_bounds__(256) void gather_channels(
    const float* __restrict__ x, const int* __restrict__ idx,
    float* __restrict__ out, int k) {
  const int slot = blockIdx.y;  // b*k + r
  const int b = slot / k;
  const long CH4 = (long)DD * HW / 4;  // 262144 float4 per channel
  const int c = idx[slot];
  const float4* src =
      reinterpret_cast<const float4*>(x) + ((long)b * CC + c) * CH4;
  float4* dst = reinterpret_cast<float4*>(out) + (long)slot * CH4;
  for (long g = blockIdx.x * (long)blockDim.x + threadIdx.x; g < CH4;
       g += (long)gridDim.x * blockDim.x) {
    dst[g] = src[g];
  }
}

extern "C" void kernel_launch(void* const* d_in, const int* in_sizes, int n_in,
                              void* d_out, int out_size, void* d_ws,
                              size_t ws_size, hipStream_t stream) {
  const float* x = (const float*)d_in[0];
  float* out = (float*)d_out;

  const int k = out_size / (BB * DD * HH * WW);  // = 32

  // workspace layout (fully written before read every call)
  float* partials = (float*)d_ws;                         // B*C*NPART floats
  int* idx = (int*)(partials + (size_t)BB * CC * NPART);  // B*k ints

  dim3 g1(NHT, BB * CC);  // 8 x 128 = 1024 blocks = 4/CU exactly
  lap_score_partial<<<g1, 256, 0, stream>>>(x, partials);

  score_topk<<<BB, CC, 0, stream>>>(partials, idx, k);

  dim3 g3(128, BB * k);
  gather_channels<<<g3, 256, 0, stream>>>(x, idx, out, k);
}

// Round 4
// 214.685 us; speedup vs baseline: 3.1694x; 3.1694x over previous
//
#include <hip/hip_runtime.h>
#include <math.h>

// Problem constants (fixed by setup_inputs)
#define BB 2
#define CC 64
#define DD 64
#define HH 128
#define WW 128
#define HW (HH * WW)

#define ROWS_PER_BLOCK 16          // 8 hr-groups x 2 rows/thread
#define NHT (HH / ROWS_PER_BLOCK)  // 8
#define NPART NHT                  // 8 partials per (b,c)

// ---------------------------------------------------------------------------
// Kernel 1: streaming 19-tap Laplacian, per-block partial |lap| sum.
//   S5(d) = -6*c + (N+S+E+W)                  (outer slices)
//   S9(d) = 24*c - 6*(N+S+E+W) + diagonals    (mid slice)
//   lap(d) = S9(d) + S5(d-1) + S5(d+1)        (zero pad outside volume)
// Thread owns (h0..h0+1, w0..w0+3); whole d-range per block; w-halo via
// shuffles. 1-deep pipeline with NAMED float4 double buffers — no array
// parameters anywhere (R3's scratch-spill bug).
// ---------------------------------------------------------------------------
__global__ __launch_bounds__(256, 4) void lap_score_partial(
    const float* __restrict__ x, float* __restrict__ partials) {
  const int ht  = blockIdx.x;
  const int bc  = blockIdx.y;
  const int tid = threadIdx.x;
  const int hr  = tid >> 5;  // 0..7
  const int wg  = tid & 31;  // 0..31
  const int h0  = ht * ROWS_PER_BLOCK + hr * 2;
  const int w0  = wg * 4;

  const float* chan = x + (size_t)bc * ((size_t)DD * HW);

  // rows h0-1 .. h0+2: clamped offsets + zero masks (uniform over d)
  const int hm = h0 - 1, hq = h0 + 2;
  const float m0 = (hm >= 0) ? 1.f : 0.f;
  const float m3 = (hq < HH) ? 1.f : 0.f;
  const int off0 = ((hm >= 0) ? hm : 0) * WW + w0;
  const int off1 = h0 * WW + w0;
  const int off2 = (h0 + 1) * WW + w0;
  const int off3 = ((hq < HH) ? hq : HH - 1) * WW + w0;

#define LOADS(dd, R0, R1, R2, R3)                      \
  do {                                                 \
    const float* sp_ = chan + (size_t)(dd) * HW;       \
    R0 = *reinterpret_cast<const float4*>(sp_ + off0); \
    R1 = *reinterpret_cast<const float4*>(sp_ + off1); \
    R2 = *reinterpret_cast<const float4*>(sp_ + off2); \
    R3 = *reinterpret_cast<const float4*>(sp_ + off3); \
  } while (0)

// per loaded row: masked centers + horizontal pair sums (halo via shuffles)
#define ROWPROC(R, M, cen, hpp)                                   \
  do {                                                            \
    float a1 = R.x * M, a2 = R.y * M, a3 = R.z * M, a4 = R.w * M; \
    float a0 = __shfl_up(a4, 1);                                  \
    a0 = (wg == 0) ? 0.f : a0;                                    \
    float a5 = __shfl_down(a1, 1);                                \
    a5 = (wg == 31) ? 0.f : a5;                                   \
    cen[0] = a1; cen[1] = a2; cen[2] = a3; cen[3] = a4;           \
    hpp[0] = a0 + a2; hpp[1] = a1 + a3;                           \
    hpp[2] = a2 + a4; hpp[3] = a3 + a5;                           \
  } while (0)

// S5,S9 (2 rows x 4 cols) of a loaded slice held in R0..R3
#define CONSUME(R0, R1, R2, R3, s5, s9)                                       \
  do {                                                                        \
    float cen[4][4], hpp[4][4];                                               \
    ROWPROC(R0, m0, cen[0], hpp[0]);                                          \
    ROWPROC(R1, 1.f, cen[1], hpp[1]);                                         \
    ROWPROC(R2, 1.f, cen[2], hpp[2]);                                         \
    ROWPROC(R3, m3, cen[3], hpp[3]);                                          \
    _Pragma("unroll") for (int i_ = 0; i_ < 2; ++i_)                          \
    _Pragma("unroll") for (int j_ = 0; j_ < 4; ++j_) {                        \
      float c_ = cen[i_ + 1][j_];                                             \
      float t_ = hpp[i_ + 1][j_] + cen[i_][j_] + cen[i_ + 2][j_];             \
      s5[i_][j_] = fmaf(-6.f, c_, t_);                                        \
      s9[i_][j_] =                                                            \
          fmaf(24.f, c_, fmaf(-6.f, t_, hpp[i_][j_] + hpp[i_ + 2][j_]));      \
    }                                                                         \
  } while (0)

#define ACCSHIFT()                                             \
  do {                                                         \
    _Pragma("unroll") for (int i_ = 0; i_ < 2; ++i_)           \
    _Pragma("unroll") for (int j_ = 0; j_ < 4; ++j_) {         \
      acc += fabsf(s9c[i_][j_] + s5p[i_][j_] + s5n[i_][j_]);   \
      s5p[i_][j_] = s5c[i_][j_];                               \
      s5c[i_][j_] = s5n[i_][j_];                               \
      s9c[i_][j_] = s9n[i_][j_];                               \
    }                                                          \
  } while (0)

  float4 A0, A1, A2, A3, B0, B1, B2, B3;
  float s5p[2][4], s5c[2][4], s9c[2][4], s5n[2][4], s9n[2][4];
  float acc = 0.f;

  LOADS(0, A0, A1, A2, A3);
  LOADS(1, B0, B1, B2, B3);
  CONSUME(A0, A1, A2, A3, s5c, s9c);  // slice 0
#pragma unroll
  for (int i_ = 0; i_ < 2; ++i_)
#pragma unroll
    for (int j_ = 0; j_ < 4; ++j_) s5p[i_][j_] = 0.f;  // S5(-1)=0

  for (int d = 0; d < DD - 2; d += 2) {
    LOADS(d + 2, A0, A1, A2, A3);       // prefetch into freed A
    CONSUME(B0, B1, B2, B3, s5n, s9n);  // slice d+1
    ACCSHIFT();                         // output d
    LOADS(d + 3, B0, B1, B2, B3);       // prefetch into freed B
    CONSUME(A0, A1, A2, A3, s5n, s9n);  // slice d+2
    ACCSHIFT();                         // output d+1
  }
  // outputs 62 and 63
  CONSUME(B0, B1, B2, B3, s5n, s9n);  // slice 63
  ACCSHIFT();                         // output 62
#pragma unroll
  for (int i_ = 0; i_ < 2; ++i_)
#pragma unroll
    for (int j_ = 0; j_ < 4; ++j_) { s5n[i_][j_] = 0.f; s9n[i_][j_] = 0.f; }
  ACCSHIFT();  // output 63 (S5(64)=0)

  // deterministic block tree reduction
  __shared__ float red[256];
  red[tid] = acc;
  __syncthreads();
  for (int s = 128; s > 0; s >>= 1) {
    if (tid < s) red[tid] += red[tid + s];
    __syncthreads();
  }
  if (tid == 0) partials[(size_t)bc * NPART + ht] = red[0];

#undef LOADS
#undef ROWPROC
#undef CONSUME
#undef ACCSHIFT
}

// ---------------------------------------------------------------------------
// Kernel 2: fused score-reduce + top-k rank selection.
// Matches jax.lax.top_k: descending, ties -> lower index first.
// ---------------------------------------------------------------------------
__global__ void score_topk(const float* __restrict__ partials,
                           int* __restrict__ idx, int k) {
  const int b = blockIdx.x;
  const int c = threadIdx.x;  // 0..C-1
  const float* pp = partials + (size_t)(b * CC + c) * NPART;
  float s = 0.f;
#pragma unroll
  for (int i = 0; i < NPART; ++i) s += pp[i];  // fixed serial order
  __shared__ float sm[CC];
  sm[c] = s;
  __syncthreads();
  int rank = 0;
  for (int j = 0; j < CC; ++j) {
    float u = sm[j];
    rank += (u > s) || (u == s && j < c);
  }
  if (rank < k) idx[b * k + rank] = c;
}

// ---------------------------------------------------------------------------
// Kernel 3: gather selected channels (pure float4 copy).
// ---------------------------------------------------------------------------
__global__ __launch_bounds__(256) void gather_channels(
    const float* __restrict__ x, const int* __restrict__ idx,
    float* __restrict__ out, int k) {
  const int slot = blockIdx.y;  // b*k + r
  const int b = slot / k;
  const long CH4 = (long)DD * HW / 4;  // 262144 float4 per channel
  const int c = idx[slot];
  const float4* src =
      reinterpret_cast<const float4*>(x) + ((long)b * CC + c) * CH4;
  float4* dst = reinterpret_cast<float4*>(out) + (long)slot * CH4;
  for (long g = blockIdx.x * (long)blockDim.x + threadIdx.x; g < CH4;
       g += (long)gridDim.x * blockDim.x) {
    dst[g] = src[g];
  }
}

extern "C" void kernel_launch(void* const* d_in, const int* in_sizes, int n_in,
                              void* d_out, int out_size, void* d_ws,
                              size_t ws_size, hipStream_t stream) {
  const float* x = (const float*)d_in[0];
  float* out = (float*)d_out;

  const int k = out_size / (BB * DD * HH * WW);  // = 32

  // workspace layout (fully written before read every call)
  float* partials = (float*)d_ws;                         // B*C*NPART floats
  int* idx = (int*)(partials + (size_t)BB * CC * NPART);  // B*k ints

  dim3 g1(NHT, BB * CC);  // 8 x 128 = 1024 blocks = 4/CU exactly
  lap_score_partial<<<g1, 256, 0, stream>>>(x, partials);

  score_topk<<<BB, CC, 0, stream>>>(partials, idx, k);

  dim3 g3(128, BB * k);
  gather_channels<<<g3, 256, 0, stream>>>(x, idx, out, k);
}

// Round 5
// 191.363 us; speedup vs baseline: 3.5556x; 1.1219x over previous
//
#include <hip/hip_runtime.h>
#include <math.h>

// Problem constants (fixed by setup_inputs)
#define BB 2
#define CC 64
#define DD 64
#define HH 128
#define WW 128
#define HW (HH * WW)

#define ROWS_PER_BLOCK 16          // 8 hr-groups x 2 rows/thread
#define NHT (HH / ROWS_PER_BLOCK)  // 8
#define NPART NHT                  // 8 partials per (b,c)

typedef float f32x4 __attribute__((ext_vector_type(4)));

// ---------------------------------------------------------------------------
// Kernel 1: streaming 19-tap Laplacian, per-block partial |lap| sum.
//   S5(d) = -6*c + (N+S+E+W)                  (outer slices)
//   S9(d) = 24*c - 6*(N+S+E+W) + diagonals    (mid slice)
//   lap(d) = S9(d) + S5(d-1) + S5(d+1)        (zero pad outside volume)
// Thread owns (h0..h0+1, w0..w0+3); whole d-range per block; w-halo via
// shuffles; named float4 double buffers (no array params -> no scratch).
// Grid: bc FASTEST so all 8 ht-tiles of a channel map to the same XCD ->
// h-halo re-reads hit that XCD's L2 instead of HBM.
// ---------------------------------------------------------------------------
__global__ __launch_bounds__(256, 4) void lap_score_partial(
    const float* __restrict__ x, float* __restrict__ partials) {
  const int bc  = blockIdx.x;  // fastest: channel -> fixed XCD
  const int ht  = blockIdx.y;
  const int tid = threadIdx.x;
  const int hr  = tid >> 5;  // 0..7
  const int wg  = tid & 31;  // 0..31
  const int h0  = ht * ROWS_PER_BLOCK + hr * 2;
  const int w0  = wg * 4;

  const float* chan = x + (size_t)bc * ((size_t)DD * HW);

  // rows h0-1 .. h0+2: clamped offsets + zero masks (uniform over d)
  const int hm = h0 - 1, hq = h0 + 2;
  const float m0 = (hm >= 0) ? 1.f : 0.f;
  const float m3 = (hq < HH) ? 1.f : 0.f;
  const int off0 = ((hm >= 0) ? hm : 0) * WW + w0;
  const int off1 = h0 * WW + w0;
  const int off2 = (h0 + 1) * WW + w0;
  const int off3 = ((hq < HH) ? hq : HH - 1) * WW + w0;

#define LOADS(dd, R0, R1, R2, R3)                      \
  do {                                                 \
    const float* sp_ = chan + (size_t)(dd) * HW;       \
    R0 = *reinterpret_cast<const float4*>(sp_ + off0); \
    R1 = *reinterpret_cast<const float4*>(sp_ + off1); \
    R2 = *reinterpret_cast<const float4*>(sp_ + off2); \
    R3 = *reinterpret_cast<const float4*>(sp_ + off3); \
  } while (0)

// per loaded row: masked centers + horizontal pair sums (halo via shuffles)
#define ROWPROC(R, M, cen, hpp)                                   \
  do {                                                            \
    float a1 = R.x * M, a2 = R.y * M, a3 = R.z * M, a4 = R.w * M; \
    float a0 = __shfl_up(a4, 1);                                  \
    a0 = (wg == 0) ? 0.f : a0;                                    \
    float a5 = __shfl_down(a1, 1);                                \
    a5 = (wg == 31) ? 0.f : a5;                                   \
    cen[0] = a1; cen[1] = a2; cen[2] = a3; cen[3] = a4;           \
    hpp[0] = a0 + a2; hpp[1] = a1 + a3;                           \
    hpp[2] = a2 + a4; hpp[3] = a3 + a5;                           \
  } while (0)

// S5,S9 (2 rows x 4 cols) of a loaded slice held in R0..R3
#define CONSUME(R0, R1, R2, R3, s5, s9)                                       \
  do {                                                                        \
    float cen[4][4], hpp[4][4];                                               \
    ROWPROC(R0, m0, cen[0], hpp[0]);                                          \
    ROWPROC(R1, 1.f, cen[1], hpp[1]);                                         \
    ROWPROC(R2, 1.f, cen[2], hpp[2]);                                         \
    ROWPROC(R3, m3, cen[3], hpp[3]);                                          \
    _Pragma("unroll") for (int i_ = 0; i_ < 2; ++i_)                          \
    _Pragma("unroll") for (int j_ = 0; j_ < 4; ++j_) {                        \
      float c_ = cen[i_ + 1][j_];                                             \
      float t_ = hpp[i_ + 1][j_] + cen[i_][j_] + cen[i_ + 2][j_];             \
      s5[i_][j_] = fmaf(-6.f, c_, t_);                                        \
      s9[i_][j_] =                                                            \
          fmaf(24.f, c_, fmaf(-6.f, t_, hpp[i_][j_] + hpp[i_ + 2][j_]));      \
    }                                                                         \
  } while (0)

#define ACCSHIFT()                                             \
  do {                                                         \
    _Pragma("unroll") for (int i_ = 0; i_ < 2; ++i_)           \
    _Pragma("unroll") for (int j_ = 0; j_ < 4; ++j_) {         \
      acc += fabsf(s9c[i_][j_] + s5p[i_][j_] + s5n[i_][j_]);   \
      s5p[i_][j_] = s5c[i_][j_];                               \
      s5c[i_][j_] = s5n[i_][j_];                               \
      s9c[i_][j_] = s9n[i_][j_];                               \
    }                                                          \
  } while (0)

  float4 A0, A1, A2, A3, B0, B1, B2, B3;
  float s5p[2][4], s5c[2][4], s9c[2][4], s5n[2][4], s9n[2][4];
  float acc = 0.f;

  LOADS(0, A0, A1, A2, A3);
  LOADS(1, B0, B1, B2, B3);
  CONSUME(A0, A1, A2, A3, s5c, s9c);  // slice 0
#pragma unroll
  for (int i_ = 0; i_ < 2; ++i_)
#pragma unroll
    for (int j_ = 0; j_ < 4; ++j_) s5p[i_][j_] = 0.f;  // S5(-1)=0

  for (int d = 0; d < DD - 2; d += 2) {
    LOADS(d + 2, A0, A1, A2, A3);       // prefetch into freed A
    CONSUME(B0, B1, B2, B3, s5n, s9n);  // slice d+1
    ACCSHIFT();                         // output d
    LOADS(d + 3, B0, B1, B2, B3);       // prefetch into freed B
    CONSUME(A0, A1, A2, A3, s5n, s9n);  // slice d+2
    ACCSHIFT();                         // output d+1
  }
  // outputs 62 and 63
  CONSUME(B0, B1, B2, B3, s5n, s9n);  // slice 63
  ACCSHIFT();                         // output 62
#pragma unroll
  for (int i_ = 0; i_ < 2; ++i_)
#pragma unroll
    for (int j_ = 0; j_ < 4; ++j_) { s5n[i_][j_] = 0.f; s9n[i_][j_] = 0.f; }
  ACCSHIFT();  // output 63 (S5(64)=0)

  // deterministic block tree reduction
  __shared__ float red[256];
  red[tid] = acc;
  __syncthreads();
  for (int s = 128; s > 0; s >>= 1) {
    if (tid < s) red[tid] += red[tid + s];
    __syncthreads();
  }
  if (tid == 0) partials[(size_t)bc * NPART + ht] = red[0];

#undef LOADS
#undef ROWPROC
#undef CONSUME
#undef ACCSHIFT
}

// ---------------------------------------------------------------------------
// Kernel 2: fused score-reduce + top-k rank selection.
// Matches jax.lax.top_k: descending, ties -> lower index first.
// ---------------------------------------------------------------------------
__global__ void score_topk(const float* __restrict__ partials,
                           int* __restrict__ idx, int k) {
  const int b = blockIdx.x;
  const int c = threadIdx.x;  // 0..C-1
  const float* pp = partials + (size_t)(b * CC + c) * NPART;
  float s = 0.f;
#pragma unroll
  for (int i = 0; i < NPART; ++i) s += pp[i];  // fixed serial order
  __shared__ float sm[CC];
  sm[c] = s;
  __syncthreads();
  int rank = 0;
  for (int j = 0; j < CC; ++j) {
    float u = sm[j];
    rank += (u > s) || (u == s && j < c);
  }
  if (rank < k) idx[b * k + rank] = c;
}

// ---------------------------------------------------------------------------
// Kernel 3: gather selected channels (float4 copy, NT stores so the 256 MB
// output write does not evict the L3-resident tail of x that pass1 left).
// ---------------------------------------------------------------------------
__global__ __launch_bounds__(256) void gather_channels(
    const float* __restrict__ x, const int* __restrict__ idx,
    float* __restrict__ out, int k) {
  const int slot = blockIdx.y;  // b*k + r
  const int b = slot / k;
  const long CH4 = (long)DD * HW / 4;  // 262144 float4 per channel
  const int c = idx[slot];
  const f32x4* src =
      reinterpret_cast<const f32x4*>(x) + ((long)b * CC + c) * CH4;
  f32x4* dst = reinterpret_cast<f32x4*>(out) + (long)slot * CH4;
  for (long g = blockIdx.x * (long)blockDim.x + threadIdx.x; g < CH4;
       g += (long)gridDim.x * blockDim.x) {
    f32x4 v = src[g];
    __builtin_nontemporal_store(v, &dst[g]);
  }
}

extern "C" void kernel_launch(void* const* d_in, const int* in_sizes, int n_in,
                              void* d_out, int out_size, void* d_ws,
                              size_t ws_size, hipStream_t stream) {
  const float* x = (const float*)d_in[0];
  float* out = (float*)d_out;

  const int k = out_size / (BB * DD * HH * WW);  // = 32

  // workspace layout (fully written before read every call)
  float* partials = (float*)d_ws;                         // B*C*NPART floats
  int* idx = (int*)(partials + (size_t)BB * CC * NPART);  // B*k ints

  // bc fastest (128 % 8 == 0): all ht-tiles of a channel on one XCD
  dim3 g1(BB * CC, NHT);
  lap_score_partial<<<g1, 256, 0, stream>>>(x, partials);

  score_topk<<<BB, CC, 0, stream>>>(partials, idx, k);

  dim3 g3(128, BB * k);
  gather_channels<<<g3, 256, 0, stream>>>(x, idx, out, k);
}

// Round 6
// 187.038 us; speedup vs baseline: 3.6378x; 1.0231x over previous
//
#include <hip/hip_runtime.h>
#include <math.h>

// Problem constants (fixed by setup_inputs)
#define BB 2
#define CC 64
#define DD 64
#define HH 128
#define WW 128
#define HW (HH * WW)

#define ROWS_PER_BLOCK 16          // 8 hr-groups x 2 rows/thread
#define NHT (HH / ROWS_PER_BLOCK)  // 8
#define NPART NHT                  // 8 partials per (b,c)

typedef float f32x4 __attribute__((ext_vector_type(4)));

// ---------------------------------------------------------------------------
// Kernel 1: streaming 19-tap Laplacian, per-block partial |lap| sum.
//   S5(d) = -6*c + (N+S+E+W)                  (outer slices)
//   S9(d) = 24*c - 6*(N+S+E+W) + diagonals    (mid slice)
//   lap(d) = S9(d) + S5(d-1) + S5(d+1)        (zero pad outside volume)
// Thread owns (h0..h0+1, w0..w0+3); whole d-range per block; w-halo via
// shuffles; named float4 double buffers (no array params -> no scratch).
// Grid: bc FASTEST so all 8 ht-tiles of a channel map to the same XCD ->
// h-halo re-reads hit that XCD's L2 instead of HBM.
// ---------------------------------------------------------------------------
__global__ __launch_bounds__(256, 4) void lap_score_partial(
    const float* __restrict__ x, float* __restrict__ partials) {
  const int bc  = blockIdx.x;  // fastest: channel -> fixed XCD
  const int ht  = blockIdx.y;
  const int tid = threadIdx.x;
  const int hr  = tid >> 5;  // 0..7
  const int wg  = tid & 31;  // 0..31
  const int h0  = ht * ROWS_PER_BLOCK + hr * 2;
  const int w0  = wg * 4;

  const float* chan = x + (size_t)bc * ((size_t)DD * HW);

  // rows h0-1 .. h0+2: clamped offsets + zero masks (uniform over d)
  const int hm = h0 - 1, hq = h0 + 2;
  const float m0 = (hm >= 0) ? 1.f : 0.f;
  const float m3 = (hq < HH) ? 1.f : 0.f;
  const int off0 = ((hm >= 0) ? hm : 0) * WW + w0;
  const int off1 = h0 * WW + w0;
  const int off2 = (h0 + 1) * WW + w0;
  const int off3 = ((hq < HH) ? hq : HH - 1) * WW + w0;

#define LOADS(dd, R0, R1, R2, R3)                      \
  do {                                                 \
    const float* sp_ = chan + (size_t)(dd) * HW;       \
    R0 = *reinterpret_cast<const float4*>(sp_ + off0); \
    R1 = *reinterpret_cast<const float4*>(sp_ + off1); \
    R2 = *reinterpret_cast<const float4*>(sp_ + off2); \
    R3 = *reinterpret_cast<const float4*>(sp_ + off3); \
  } while (0)

// per loaded row: masked centers + horizontal pair sums (halo via shuffles)
#define ROWPROC(R, M, cen, hpp)                                   \
  do {                                                            \
    float a1 = R.x * M, a2 = R.y * M, a3 = R.z * M, a4 = R.w * M; \
    float a0 = __shfl_up(a4, 1);                                  \
    a0 = (wg == 0) ? 0.f : a0;                                    \
    float a5 = __shfl_down(a1, 1);                                \
    a5 = (wg == 31) ? 0.f : a5;                                   \
    cen[0] = a1; cen[1] = a2; cen[2] = a3; cen[3] = a4;           \
    hpp[0] = a0 + a2; hpp[1] = a1 + a3;                           \
    hpp[2] = a2 + a4; hpp[3] = a3 + a5;                           \
  } while (0)

// S5,S9 (2 rows x 4 cols) of a loaded slice held in R0..R3
#define CONSUME(R0, R1, R2, R3, s5, s9)                                       \
  do {                                                                        \
    float cen[4][4], hpp[4][4];                                               \
    ROWPROC(R0, m0, cen[0], hpp[0]);                                          \
    ROWPROC(R1, 1.f, cen[1], hpp[1]);                                         \
    ROWPROC(R2, 1.f, cen[2], hpp[2]);                                         \
    ROWPROC(R3, m3, cen[3], hpp[3]);                                          \
    _Pragma("unroll") for (int i_ = 0; i_ < 2; ++i_)                          \
    _Pragma("unroll") for (int j_ = 0; j_ < 4; ++j_) {                        \
      float c_ = cen[i_ + 1][j_];                                             \
      float t_ = hpp[i_ + 1][j_] + cen[i_][j_] + cen[i_ + 2][j_];             \
      s5[i_][j_] = fmaf(-6.f, c_, t_);                                        \
      s9[i_][j_] =                                                            \
          fmaf(24.f, c_, fmaf(-6.f, t_, hpp[i_][j_] + hpp[i_ + 2][j_]));      \
    }                                                                         \
  } while (0)

#define ACCSHIFT()                                             \
  do {                                                         \
    _Pragma("unroll") for (int i_ = 0; i_ < 2; ++i_)           \
    _Pragma("unroll") for (int j_ = 0; j_ < 4; ++j_) {         \
      acc += fabsf(s9c[i_][j_] + s5p[i_][j_] + s5n[i_][j_]);   \
      s5p[i_][j_] = s5c[i_][j_];                               \
      s5c[i_][j_] = s5n[i_][j_];                               \
      s9c[i_][j_] = s9n[i_][j_];                               \
    }                                                          \
  } while (0)

  float4 A0, A1, A2, A3, B0, B1, B2, B3;
  float s5p[2][4], s5c[2][4], s9c[2][4], s5n[2][4], s9n[2][4];
  float acc = 0.f;

  LOADS(0, A0, A1, A2, A3);
  LOADS(1, B0, B1, B2, B3);
  CONSUME(A0, A1, A2, A3, s5c, s9c);  // slice 0
#pragma unroll
  for (int i_ = 0; i_ < 2; ++i_)
#pragma unroll
    for (int j_ = 0; j_ < 4; ++j_) s5p[i_][j_] = 0.f;  // S5(-1)=0

  for (int d = 0; d < DD - 2; d += 2) {
    LOADS(d + 2, A0, A1, A2, A3);       // prefetch into freed A
    CONSUME(B0, B1, B2, B3, s5n, s9n);  // slice d+1
    ACCSHIFT();                         // output d
    LOADS(d + 3, B0, B1, B2, B3);       // prefetch into freed B
    CONSUME(A0, A1, A2, A3, s5n, s9n);  // slice d+2
    ACCSHIFT();                         // output d+1
  }
  // outputs 62 and 63
  CONSUME(B0, B1, B2, B3, s5n, s9n);  // slice 63
  ACCSHIFT();                         // output 62
#pragma unroll
  for (int i_ = 0; i_ < 2; ++i_)
#pragma unroll
    for (int j_ = 0; j_ < 4; ++j_) { s5n[i_][j_] = 0.f; s9n[i_][j_] = 0.f; }
  ACCSHIFT();  // output 63 (S5(64)=0)

  // deterministic block tree reduction
  __shared__ float red[256];
  red[tid] = acc;
  __syncthreads();
  for (int s = 128; s > 0; s >>= 1) {
    if (tid < s) red[tid] += red[tid + s];
    __syncthreads();
  }
  if (tid == 0) partials[(size_t)bc * NPART + ht] = red[0];

#undef LOADS
#undef ROWPROC
#undef CONSUME
#undef ACCSHIFT
}

// ---------------------------------------------------------------------------
// Kernel 2: fused score-reduce + top-k rank selection.
// Matches jax.lax.top_k: descending, ties -> lower index first.
// ---------------------------------------------------------------------------
__global__ void score_topk(const float* __restrict__ partials,
                           int* __restrict__ idx, int k) {
  const int b = blockIdx.x;
  const int c = threadIdx.x;  // 0..C-1
  const float* pp = partials + (size_t)(b * CC + c) * NPART;
  float s = 0.f;
#pragma unroll
  for (int i = 0; i < NPART; ++i) s += pp[i];  // fixed serial order
  __shared__ float sm[CC];
  sm[c] = s;
  __syncthreads();
  int rank = 0;
  for (int j = 0; j < CC; ++j) {
    float u = sm[j];
    rank += (u > s) || (u == s && j < c);
  }
  if (rank < k) idx[b * k + rank] = c;
}

// ---------------------------------------------------------------------------
// Kernel 3: gather selected channels. Pass1 leaves the d-tail (~d>=32) of
// every channel L3-resident; walk chunks HIGH-d -> LOW-d so those reads hit
// L3 before being evicted. NT loads keep the miss reads from evicting the
// not-yet-read tail; NT stores keep the 256 MB output write out of L3.
// ---------------------------------------------------------------------------
__global__ __launch_bounds__(256) void gather_channels(
    const float* __restrict__ x, const int* __restrict__ idx,
    float* __restrict__ out, int k) {
  const int slot = blockIdx.y;  // b*k + r
  const int b = slot / k;
  const long CH4 = (long)DD * HW / 4;  // 262144 float4 per channel
  const int c = idx[slot];
  const f32x4* src =
      reinterpret_cast<const f32x4*>(x) + ((long)b * CC + c) * CH4;
  f32x4* dst = reinterpret_cast<f32x4*>(out) + (long)slot * CH4;
  const long stride = (long)gridDim.x * blockDim.x;      // float4 per round
  const long nIt = CH4 / stride;                         // 8 (evenly divides)
  const long lane = blockIdx.x * (long)blockDim.x + threadIdx.x;
  for (long it = nIt - 1; it >= 0; --it) {               // high d first
    const long g = it * stride + lane;
    f32x4 v = __builtin_nontemporal_load(&src[g]);
    __builtin_nontemporal_store(v, &dst[g]);
  }
}

extern "C" void kernel_launch(void* const* d_in, const int* in_sizes, int n_in,
                              void* d_out, int out_size, void* d_ws,
                              size_t ws_size, hipStream_t stream) {
  const float* x = (const float*)d_in[0];
  float* out = (float*)d_out;

  const int k = out_size / (BB * DD * HH * WW);  // = 32

  // workspace layout (fully written before read every call)
  float* partials = (float*)d_ws;                         // B*C*NPART floats
  int* idx = (int*)(partials + (size_t)BB * CC * NPART);  // B*k ints

  // bc fastest (128 % 8 == 0): all ht-tiles of a channel on one XCD
  dim3 g1(BB * CC, NHT);
  lap_score_partial<<<g1, 256, 0, stream>>>(x, partials);

  score_topk<<<BB, CC, 0, stream>>>(partials, idx, k);

  dim3 g3(128, BB * k);
  gather_channels<<<g3, 256, 0, stream>>>(x, idx, out, k);
}

// Round 8
// 185.817 us; speedup vs baseline: 3.6617x; 1.0066x over previous
//
#include <hip/hip_runtime.h>
#include <math.h>

// Problem constants (fixed by setup_inputs)
#define BB 2
#define CC 64
#define DD 64
#define HH 128
#define WW 128
#define HW (HH * WW)

#define ROWS_PER_BLOCK 16          // 8 hr-groups x 2 rows/thread
#define NHT (HH / ROWS_PER_BLOCK)  // 8
#define NPART NHT                  // 8 partials per (b,c)

typedef float f32x4 __attribute__((ext_vector_type(4)));

// ---------------------------------------------------------------------------
// Kernel 1: streaming 19-tap Laplacian, per-block partial |lap| sum.
//   S5(d) = -6*c + (N+S+E+W)                  (outer slices)
//   S9(d) = 24*c - 6*(N+S+E+W) + diagonals    (mid slice)
//   lap(d) = S9(d) + S5(d-1) + S5(d+1)        (zero pad outside volume)
// Thread owns (h0..h0+1, w0..w0+3); whole d-range per block; w-halo via
// shuffles; named float4 double buffers (no array params -> no scratch).
// Grid: bc FASTEST so all 8 ht-tiles of a channel map to the same XCD ->
// h-halo re-reads hit that XCD's L2 instead of HBM.  (Proven in R4-R6.)
// ---------------------------------------------------------------------------
__global__ __launch_bounds__(256, 4) void lap_score_partial(
    const float* __restrict__ x, float* __restrict__ partials) {
  const int bc  = blockIdx.x;  // fastest: channel -> fixed XCD
  const int ht  = blockIdx.y;
  const int tid = threadIdx.x;
  const int hr  = tid >> 5;  // 0..7
  const int wg  = tid & 31;  // 0..31
  const int h0  = ht * ROWS_PER_BLOCK + hr * 2;
  const int w0  = wg * 4;

  const float* chan = x + (size_t)bc * ((size_t)DD * HW);

  // rows h0-1 .. h0+2: clamped offsets + zero masks (uniform over d)
  const int hm = h0 - 1, hq = h0 + 2;
  const float m0 = (hm >= 0) ? 1.f : 0.f;
  const float m3 = (hq < HH) ? 1.f : 0.f;
  const int off0 = ((hm >= 0) ? hm : 0) * WW + w0;
  const int off1 = h0 * WW + w0;
  const int off2 = (h0 + 1) * WW + w0;
  const int off3 = ((hq < HH) ? hq : HH - 1) * WW + w0;

#define LOADS(dd, R0, R1, R2, R3)                      \
  do {                                                 \
    const float* sp_ = chan + (size_t)(dd) * HW;       \
    R0 = *reinterpret_cast<const float4*>(sp_ + off0); \
    R1 = *reinterpret_cast<const float4*>(sp_ + off1); \
    R2 = *reinterpret_cast<const float4*>(sp_ + off2); \
    R3 = *reinterpret_cast<const float4*>(sp_ + off3); \
  } while (0)

// per loaded row: masked centers + horizontal pair sums (halo via shuffles)
#define ROWPROC(R, M, cen, hpp)                                   \
  do {                                                            \
    float a1 = R.x * M, a2 = R.y * M, a3 = R.z * M, a4 = R.w * M; \
    float a0 = __shfl_up(a4, 1);                                  \
    a0 = (wg == 0) ? 0.f : a0;                                    \
    float a5 = __shfl_down(a1, 1);                                \
    a5 = (wg == 31) ? 0.f : a5;                                   \
    cen[0] = a1; cen[1] = a2; cen[2] = a3; cen[3] = a4;           \
    hpp[0] = a0 + a2; hpp[1] = a1 + a3;                           \
    hpp[2] = a2 + a4; hpp[3] = a3 + a5;                           \
  } while (0)

// S5,S9 (2 rows x 4 cols) of a loaded slice held in R0..R3
#define CONSUME(R0, R1, R2, R3, s5, s9)                                       \
  do {                                                                        \
    float cen[4][4], hpp[4][4];                                               \
    ROWPROC(R0, m0, cen[0], hpp[0]);                                          \
    ROWPROC(R1, 1.f, cen[1], hpp[1]);                                         \
    ROWPROC(R2, 1.f, cen[2], hpp[2]);                                         \
    ROWPROC(R3, m3, cen[3], hpp[3]);                                          \
    _Pragma("unroll") for (int i_ = 0; i_ < 2; ++i_)                          \
    _Pragma("unroll") for (int j_ = 0; j_ < 4; ++j_) {                        \
      float c_ = cen[i_ + 1][j_];                                             \
      float t_ = hpp[i_ + 1][j_] + cen[i_][j_] + cen[i_ + 2][j_];             \
      s5[i_][j_] = fmaf(-6.f, c_, t_);                                        \
      s9[i_][j_] =                                                            \
          fmaf(24.f, c_, fmaf(-6.f, t_, hpp[i_][j_] + hpp[i_ + 2][j_]));      \
    }                                                                         \
  } while (0)

#define ACCSHIFT()                                             \
  do {                                                         \
    _Pragma("unroll") for (int i_ = 0; i_ < 2; ++i_)           \
    _Pragma("unroll") for (int j_ = 0; j_ < 4; ++j_) {         \
      acc += fabsf(s9c[i_][j_] + s5p[i_][j_] + s5n[i_][j_]);   \
      s5p[i_][j_] = s5c[i_][j_];                               \
      s5c[i_][j_] = s5n[i_][j_];                               \
      s9c[i_][j_] = s9n[i_][j_];                               \
    }                                                          \
  } while (0)

  float4 A0, A1, A2, A3, B0, B1, B2, B3;
  float s5p[2][4], s5c[2][4], s9c[2][4], s5n[2][4], s9n[2][4];
  float acc = 0.f;

  LOADS(0, A0, A1, A2, A3);
  LOADS(1, B0, B1, B2, B3);
  CONSUME(A0, A1, A2, A3, s5c, s9c);  // slice 0
#pragma unroll
  for (int i_ = 0; i_ < 2; ++i_)
#pragma unroll
    for (int j_ = 0; j_ < 4; ++j_) s5p[i_][j_] = 0.f;  // S5(-1)=0

  for (int d = 0; d < DD - 2; d += 2) {
    LOADS(d + 2, A0, A1, A2, A3);       // prefetch into freed A
    CONSUME(B0, B1, B2, B3, s5n, s9n);  // slice d+1
    ACCSHIFT();                         // output d
    LOADS(d + 3, B0, B1, B2, B3);       // prefetch into freed B
    CONSUME(A0, A1, A2, A3, s5n, s9n);  // slice d+2
    ACCSHIFT();                         // output d+1
  }
  // outputs 62 and 63
  CONSUME(B0, B1, B2, B3, s5n, s9n);  // slice 63
  ACCSHIFT();                         // output 62
#pragma unroll
  for (int i_ = 0; i_ < 2; ++i_)
#pragma unroll
    for (int j_ = 0; j_ < 4; ++j_) { s5n[i_][j_] = 0.f; s9n[i_][j_] = 0.f; }
  ACCSHIFT();  // output 63 (S5(64)=0)

  // deterministic block tree reduction
  __shared__ float red[256];
  red[tid] = acc;
  __syncthreads();
  for (int s = 128; s > 0; s >>= 1) {
    if (tid < s) red[tid] += red[tid + s];
    __syncthreads();
  }
  if (tid == 0) partials[(size_t)bc * NPART + ht] = red[0];

#undef LOADS
#undef ROWPROC
#undef CONSUME
#undef ACCSHIFT
}

// ---------------------------------------------------------------------------
// Kernel 2: fused top-k + gather. Every block redundantly recomputes the
// top-k from the 4 KB partials table (L2-resident after the first reads;
// ~100 LDS/VALU ops), then copies its stripe of the selected channel.
// Rank-select matches jax.lax.top_k: descending, ties -> lower index first.
// Copy walks HIGH d -> LOW d (pass1's L3-resident tail first), NT load+store.
// ---------------------------------------------------------------------------
__global__ __launch_bounds__(256) void topk_gather(
    const float* __restrict__ x, const float* __restrict__ partials,
    float* __restrict__ out, int k) {
  const int tid = threadIdx.x;

  __shared__ float sm[BB * CC];
  __shared__ int sidx[BB * CC];  // BB*k <= BB*CC slots used
  if (tid < BB * CC) {
    const float* pp = partials + (size_t)tid * NPART;
    float s = 0.f;
#pragma unroll
    for (int i = 0; i < NPART; ++i) s += pp[i];  // fixed serial order
    sm[tid] = s;
  }
  __syncthreads();
  if (tid < BB * CC) {
    const int b = tid >> 6, c = tid & 63;
    const float v = sm[tid];
    int rank = 0;
    for (int j = 0; j < CC; ++j) {
      float u = sm[(b << 6) + j];
      rank += (u > v) || (u == v && j < c);
    }
    if (rank < k) sidx[b * k + rank] = c;
  }
  __syncthreads();

  const int slot = blockIdx.y;  // b*k + r
  const int b = slot / k;
  const int c = sidx[slot];
  const long CH4 = (long)DD * HW / 4;  // 262144 float4 per channel
  const f32x4* src =
      reinterpret_cast<const f32x4*>(x) + ((long)(b * CC + c)) * CH4;
  f32x4* dst = reinterpret_cast<f32x4*>(out) + (long)slot * CH4;
  const long stride = (long)gridDim.x * blockDim.x;  // float4 per round
  const long nIt = CH4 / stride;                     // 8 (evenly divides)
  const long lane = blockIdx.x * (long)blockDim.x + tid;
  for (long it = nIt - 1; it >= 0; --it) {  // high d first
    const long g = it * stride + lane;
    f32x4 v = __builtin_nontemporal_load(&src[g]);
    __builtin_nontemporal_store(v, &dst[g]);
  }
}

extern "C" void kernel_launch(void* const* d_in, const int* in_sizes, int n_in,
                              void* d_out, int out_size, void* d_ws,
                              size_t ws_size, hipStream_t stream) {
  const float* x = (const float*)d_in[0];
  float* out = (float*)d_out;

  const int k = out_size / (BB * DD * HH * WW);  // = 32

  // workspace layout (fully written before read every call)
  float* partials = (float*)d_ws;  // B*C*NPART floats

  // bc fastest (128 % 8 == 0): all ht-tiles of a channel on one XCD
  dim3 g1(BB * CC, NHT);
  lap_score_partial<<<g1, 256, 0, stream>>>(x, partials);

  dim3 g2(128, BB * k);
  topk_gather<<<g2, 256, 0, stream>>>(x, partials, out, k);
}